// Round 5
// baseline (44867.093 us; speedup 1.0000x reference)
//
#include <hip/hip_runtime.h>

typedef unsigned short u16;
typedef __attribute__((ext_vector_type(8))) short bf16x8;
typedef __attribute__((ext_vector_type(4))) float f32x4;

#define DI __device__ __forceinline__

DI float b2f(u16 u) { unsigned v = ((unsigned)u) << 16; float f; __builtin_memcpy(&f, &v, 4); return f; }
DI u16 f2b(float f) { unsigned v; __builtin_memcpy(&v, &f, 4); return (u16)((v + 0x7FFFu + ((v >> 16) & 1u)) >> 16); }
DI float sigm(float x) { return 1.0f / (1.0f + __expf(-x)); }
DI float tanh_(float x) { float e = __expf(-2.0f * fabsf(x)); float t = (1.0f - e) / (1.0f + e); return x < 0.0f ? -t : t; }

// Fenced grid barrier (conductor only; invalidates L2 each use).
DI void grid_sync(unsigned* cnt, unsigned target) {
  __syncthreads();
  if (threadIdx.x == 0) {
    __threadfence();
    __hip_atomic_fetch_add(cnt, 1u, __ATOMIC_RELEASE, __HIP_MEMORY_SCOPE_AGENT);
    while (__hip_atomic_load(cnt, __ATOMIC_ACQUIRE, __HIP_MEMORY_SCOPE_AGENT) < target)
      __builtin_amdgcn_s_sleep(2);
    __threadfence();
  }
  __syncthreads();
}

// Fence-free broadcast barrier: arrivals on 8 lines (16 WGs each, relaxed
// RMW); ONE master WG polls the 8 arrival lines and stores a generation
// flag; all others poll only the (read-only) flag line. No L2 inv/wb ->
// weights stay L2-resident; arrival RMWs never queue behind poll storms.
DI void grid_sync_nf(unsigned* cntb, unsigned gen, int grp, bool master) {
  asm volatile("s_waitcnt vmcnt(0)" ::: "memory");
  __syncthreads();
  if (threadIdx.x == 0)
    __hip_atomic_fetch_add(&cntb[grp * 32], 1u, __ATOMIC_RELAXED, __HIP_MEMORY_SCOPE_AGENT);
  if (master) {
    if (threadIdx.x < 8) {
      while (__hip_atomic_load(&cntb[threadIdx.x * 32], __ATOMIC_RELAXED, __HIP_MEMORY_SCOPE_AGENT) < gen * 16u)
        __builtin_amdgcn_s_sleep(1);
    }
    __syncthreads();
    if (threadIdx.x == 0)
      __hip_atomic_store(&cntb[256], gen, __ATOMIC_RELAXED, __HIP_MEMORY_SCOPE_AGENT);
  } else {
    if (threadIdx.x == 0) {
      while (__hip_atomic_load(&cntb[256], __ATOMIC_RELAXED, __HIP_MEMORY_SCOPE_AGENT) < gen)
        __builtin_amdgcn_s_sleep(1);
    }
  }
  __syncthreads();
  __builtin_amdgcn_sched_barrier(0);
}

// Packed LLC-coherent 8-byte h-store (4 bf16, contiguous cols).
DI void st_h4(u16* p, float f0, float f1, float f2, float f3) {
  uint2 pk;
  pk.x = (unsigned)f2b(f0) | ((unsigned)f2b(f1) << 16);
  pk.y = (unsigned)f2b(f2) | ((unsigned)f2b(f3) << 16);
  asm volatile("global_store_dwordx2 %0, %1, off sc0 sc1" :: "v"(p), "v"(pk) : "memory");
}

// 4 contiguous bf16 -> 4 floats (8B LLC/L2 load).
DI void ld_b4(const u16* p, float o[4]) {
  uint2 v = *(const uint2*)p;
  o[0] = b2f((u16)(v.x & 0xffff)); o[1] = b2f((u16)(v.x >> 16));
  o[2] = b2f((u16)(v.y & 0xffff)); o[3] = b2f((u16)(v.y >> 16));
}

// Stage 32 KB (16 rows x 2048 B) of h from global (sc0 sc1 = LLC-coherent)
// into LDS with the XOR-16B swizzle (row&7)<<4. 256 threads, 8 chunks each.
DI void stage32(char* lds, const u16* g, int tid) {
  const u16* p = g + tid * 8;
  bf16x8 v0, v1, v2, v3, v4, v5, v6, v7;
  asm volatile("global_load_dwordx4 %0, %1, off sc0 sc1" : "=v"(v0) : "v"(p) : "memory");
  asm volatile("global_load_dwordx4 %0, %1, off sc0 sc1" : "=v"(v1) : "v"(p + 2048) : "memory");
  asm volatile("global_load_dwordx4 %0, %1, off sc0 sc1" : "=v"(v2) : "v"(p + 4096) : "memory");
  asm volatile("global_load_dwordx4 %0, %1, off sc0 sc1" : "=v"(v3) : "v"(p + 6144) : "memory");
  asm volatile("global_load_dwordx4 %0, %1, off sc0 sc1" : "=v"(v4) : "v"(p + 8192) : "memory");
  asm volatile("global_load_dwordx4 %0, %1, off sc0 sc1" : "=v"(v5) : "v"(p + 10240) : "memory");
  asm volatile("global_load_dwordx4 %0, %1, off sc0 sc1" : "=v"(v6) : "v"(p + 12288) : "memory");
  asm volatile("global_load_dwordx4 %0, %1, off sc0 sc1" : "=v"(v7) : "v"(p + 14336) : "memory");
  asm volatile("s_waitcnt vmcnt(0)" ::: "memory");
  __builtin_amdgcn_sched_barrier(0);
  const int b0 = tid * 16;
#pragma unroll
  for (int k = 0; k < 8; k++) {
    int byte = b0 + k * 4096;
    int dst = byte ^ (((byte >> 11) & 7) << 4);
    bf16x8 vv = (k == 0) ? v0 : (k == 1) ? v1 : (k == 2) ? v2 : (k == 3) ? v3
              : (k == 4) ? v4 : (k == 5) ? v5 : (k == 6) ? v6 : v7;
    *(bf16x8*)(lds + dst) = vv;
  }
}

// Stage two 32 KB buffers with a single vmcnt drain (one LLC round trip).
DI void stage_pair(char* lds0, const u16* g0, char* lds1, const u16* g1, int tid) {
  const u16* p0 = g0 + tid * 8;
  const u16* p1 = g1 + tid * 8;
  bf16x8 a0, a1, a2, a3, a4, a5, a6, a7;
  bf16x8 b0_, b1_, b2_, b3_, b4_, b5_, b6_, b7_;
  asm volatile("global_load_dwordx4 %0, %1, off sc0 sc1" : "=v"(a0) : "v"(p0) : "memory");
  asm volatile("global_load_dwordx4 %0, %1, off sc0 sc1" : "=v"(a1) : "v"(p0 + 2048) : "memory");
  asm volatile("global_load_dwordx4 %0, %1, off sc0 sc1" : "=v"(a2) : "v"(p0 + 4096) : "memory");
  asm volatile("global_load_dwordx4 %0, %1, off sc0 sc1" : "=v"(a3) : "v"(p0 + 6144) : "memory");
  asm volatile("global_load_dwordx4 %0, %1, off sc0 sc1" : "=v"(a4) : "v"(p0 + 8192) : "memory");
  asm volatile("global_load_dwordx4 %0, %1, off sc0 sc1" : "=v"(a5) : "v"(p0 + 10240) : "memory");
  asm volatile("global_load_dwordx4 %0, %1, off sc0 sc1" : "=v"(a6) : "v"(p0 + 12288) : "memory");
  asm volatile("global_load_dwordx4 %0, %1, off sc0 sc1" : "=v"(a7) : "v"(p0 + 14336) : "memory");
  asm volatile("global_load_dwordx4 %0, %1, off sc0 sc1" : "=v"(b0_) : "v"(p1) : "memory");
  asm volatile("global_load_dwordx4 %0, %1, off sc0 sc1" : "=v"(b1_) : "v"(p1 + 2048) : "memory");
  asm volatile("global_load_dwordx4 %0, %1, off sc0 sc1" : "=v"(b2_) : "v"(p1 + 4096) : "memory");
  asm volatile("global_load_dwordx4 %0, %1, off sc0 sc1" : "=v"(b3_) : "v"(p1 + 6144) : "memory");
  asm volatile("global_load_dwordx4 %0, %1, off sc0 sc1" : "=v"(b4_) : "v"(p1 + 8192) : "memory");
  asm volatile("global_load_dwordx4 %0, %1, off sc0 sc1" : "=v"(b5_) : "v"(p1 + 10240) : "memory");
  asm volatile("global_load_dwordx4 %0, %1, off sc0 sc1" : "=v"(b6_) : "v"(p1 + 12288) : "memory");
  asm volatile("global_load_dwordx4 %0, %1, off sc0 sc1" : "=v"(b7_) : "v"(p1 + 14336) : "memory");
  asm volatile("s_waitcnt vmcnt(0)" ::: "memory");
  __builtin_amdgcn_sched_barrier(0);
  const int c0 = tid * 16;
#pragma unroll
  for (int k = 0; k < 8; k++) {
    int byte = c0 + k * 4096;
    int dst = byte ^ (((byte >> 11) & 7) << 4);
    bf16x8 va = (k == 0) ? a0 : (k == 1) ? a1 : (k == 2) ? a2 : (k == 3) ? a3
              : (k == 4) ? a4 : (k == 5) ? a5 : (k == 6) ? a6 : a7;
    bf16x8 vb = (k == 0) ? b0_ : (k == 1) ? b1_ : (k == 2) ? b2_ : (k == 3) ? b3_
              : (k == 4) ? b4_ : (k == 5) ? b5_ : (k == 6) ? b6_ : b7_;
    *(bf16x8*)(lds0 + dst) = va;
    *(bf16x8*)(lds1 + dst) = vb;
  }
}

// ---------------------------------------------------------------------------
// Batched f32 -> bf16 conversion (up to 16 tensors per launch; cum in quads).
// ---------------------------------------------------------------------------
struct CvtTab { const float* s[16]; u16* d[16]; unsigned cum[17]; };

__global__ __launch_bounds__(256) void cvt_k(CvtTab t) {
  unsigned g = blockIdx.x * 256 + threadIdx.x;
  if (g >= t.cum[16]) return;
  int j = 0;
#pragma unroll
  for (int k = 1; k < 16; k++) j += (g >= t.cum[k]) ? 1 : 0;
  unsigned e = (g - t.cum[j]) << 2;
  float4 v = *(const float4*)(t.s[j] + e);
  unsigned lo = (unsigned)f2b(v.x) | ((unsigned)f2b(v.y) << 16);
  unsigned hi = (unsigned)f2b(v.z) | ((unsigned)f2b(v.w) << 16);
  uint2 pk; pk.x = lo; pk.y = hi;
  *(uint2*)(t.d[j] + e) = pk;
}

// ---------------------------------------------------------------------------
// Generic C(M,N) = act(A(M,K) @ W(N,K)^T + bias). A,W bf16 row-major, bias f32.
// flags: 1 = bf16 out (else f32), 2 = tanh, 4 = row permute (r=p*permQ+q -> q*permP+p)
// ---------------------------------------------------------------------------
__global__ __launch_bounds__(256) void gemm_bt(
    const u16* __restrict__ A, int lda, const u16* __restrict__ W, int ldw,
    const float* __restrict__ bias, void* __restrict__ Cout,
    int N, int K, int flags, int permP, int permQ) {
  __shared__ u16 As[64 * 72];
  __shared__ u16 Bs[64 * 72];
  const int tid = threadIdx.x, lane = tid & 63, wv = tid >> 6;
  const int wm = wv >> 1, wn = wv & 1;
  const int l15 = lane & 15, q = lane >> 4;
  const int mblk = blockIdx.y * 64, nblk = blockIdx.x * 64;
  f32x4 acc[2][2];
  acc[0][0] = (f32x4){0,0,0,0}; acc[0][1] = (f32x4){0,0,0,0};
  acc[1][0] = (f32x4){0,0,0,0}; acc[1][1] = (f32x4){0,0,0,0};
  for (int kc = 0; kc < K; kc += 64) {
    __syncthreads();
    for (int i = tid; i < 1024; i += 256) {
      int mat = i >> 9, seg = i & 511;
      int row = seg >> 3, k8 = (seg & 7) << 3;
      const u16* src = mat ? W + (size_t)(nblk + row) * ldw + kc + k8
                           : A + (size_t)(mblk + row) * lda + kc + k8;
      u16* dst = (mat ? Bs : As) + row * 72 + k8;
      *(bf16x8*)dst = *(const bf16x8*)src;
    }
    __syncthreads();
#pragma unroll
    for (int ks = 0; ks < 2; ks++) {
      bf16x8 afr[2], bfr[2];
#pragma unroll
      for (int x = 0; x < 2; x++) {
        afr[x] = *(const bf16x8*)&As[(wm * 32 + x * 16 + l15) * 72 + ks * 32 + q * 8];
        bfr[x] = *(const bf16x8*)&Bs[(wn * 32 + x * 16 + l15) * 72 + ks * 32 + q * 8];
      }
#pragma unroll
      for (int mi = 0; mi < 2; mi++)
#pragma unroll
        for (int ni = 0; ni < 2; ni++)
          acc[mi][ni] = __builtin_amdgcn_mfma_f32_16x16x32_bf16(afr[mi], bfr[ni], acc[mi][ni], 0, 0, 0);
    }
  }
#pragma unroll
  for (int mi = 0; mi < 2; mi++)
#pragma unroll
    for (int ni = 0; ni < 2; ni++) {
      int gn = nblk + wn * 32 + ni * 16 + l15;
      float bv = bias ? bias[gn] : 0.0f;
#pragma unroll
      for (int r = 0; r < 4; r++) {
        int gm = mblk + wm * 32 + mi * 16 + q * 4 + r;
        float v = acc[mi][ni][r] + bv;
        if (flags & 2) v = tanh_(v);
        int dr = gm;
        if (flags & 4) { int pp = gm / permQ, qq = gm - pp * permQ; dr = qq * permP + pp; }
        if (flags & 1) ((u16*)Cout)[(size_t)dr * N + gn] = f2b(v);
        else ((float*)Cout)[(size_t)dr * N + gn] = v;
      }
    }
}

// ---------------------------------------------------------------------------
// Encoder LSTM recurrence. grid = 8 blocks: dir = blk&1, batch-group = blk>>1.
// ---------------------------------------------------------------------------
__global__ __launch_bounds__(1024) void enc_rec(
    const u16* __restrict__ pf, const u16* __restrict__ pb,
    const u16* __restrict__ Wf, const u16* __restrict__ Wb,
    u16* __restrict__ hs_out, u16* __restrict__ hT_out) {
  const int dir = blockIdx.x & 1, bg = blockIdx.x >> 1;
  const u16* pre = dir ? pb : pf;
  const u16* Whh = dir ? Wb : Wf;
  const int coff = dir * 64, rbase = bg * 16;
  __shared__ u16 hS[16 * 72];
  __shared__ u16 wS[256 * 72];
  __shared__ float cS[16 * 64];
  __shared__ float gS[16 * 256];
  const int tid = threadIdx.x, lane = tid & 63, wv = tid >> 6;
  const int l15 = lane & 15, q = lane >> 4;
  for (int i = tid; i < 2048; i += 1024) {
    int row = i >> 3, k8 = (i & 7) << 3;
    *(bf16x8*)&wS[row * 72 + k8] = *(const bf16x8*)&Whh[row * 64 + k8];
  }
  for (int i = tid; i < 16 * 72; i += 1024) hS[i] = 0;
  if (tid < 16 * 64) cS[tid] = 0.0f;
  __syncthreads();
  const int br = tid >> 6, j = tid & 63;
  for (int stp = 0; stp < 256; stp++) {
    const int t = dir ? 255 - stp : stp;
    f32x4 acc = (f32x4){0,0,0,0};
#pragma unroll
    for (int ks = 0; ks < 2; ks++) {
      bf16x8 bfr = *(const bf16x8*)&wS[(wv * 16 + l15) * 72 + ks * 32 + q * 8];
      bf16x8 afr = *(const bf16x8*)&hS[l15 * 72 + ks * 32 + q * 8];
      acc = __builtin_amdgcn_mfma_f32_16x16x32_bf16(afr, bfr, acc, 0, 0, 0);
    }
#pragma unroll
    for (int r = 0; r < 4; r++)
      gS[(q * 4 + r) * 256 + wv * 16 + l15] = acc[r];
    __syncthreads();
    const u16* pt = pre + ((size_t)t * 64 + rbase) * 256;
    {
      float gi = gS[br * 256 + j]       + b2f(pt[br * 256 + j]);
      float gf = gS[br * 256 + 64 + j]  + b2f(pt[br * 256 + 64 + j]);
      float gg = gS[br * 256 + 128 + j] + b2f(pt[br * 256 + 128 + j]);
      float go = gS[br * 256 + 192 + j] + b2f(pt[br * 256 + 192 + j]);
      float cn = sigm(gf) * cS[br * 64 + j] + sigm(gi) * tanh_(gg);
      float hn = sigm(go) * tanh_(cn);
      cS[br * 64 + j] = cn;
      u16 hv = f2b(hn);
      hS[br * 72 + j] = hv;
      if (hs_out) hs_out[((size_t)t * 64 + rbase + br) * 128 + coff + j] = hv;
    }
    __syncthreads();
  }
  if (hT_out) hT_out[(rbase + br) * 128 + coff + j] = hS[br * 72 + j];
}

// ---------------------------------------------------------------------------
// Direct-load K=1024 leg (2 M-tiles) — conductor only.
// ---------------------------------------------------------------------------
DI void leg1(f32x4 acc[2], const u16* __restrict__ A, int lda,
             const u16* __restrict__ W, int rbase, int vrow, int l15, int q) {
  const u16* a0 = A + (size_t)(rbase + l15) * lda + q * 8;
  const u16* a1 = A + (size_t)(rbase + 16 + l15) * lda + q * 8;
  const u16* w0 = W + (size_t)(vrow + l15) * 1024 + q * 8;
#pragma unroll
  for (int kk = 0; kk < 32; kk++) {
    bf16x8 af0 = *(const bf16x8*)(a0 + kk * 32);
    bf16x8 af1 = *(const bf16x8*)(a1 + kk * 32);
    bf16x8 bf = *(const bf16x8*)(w0 + kk * 32);
    acc[0] = __builtin_amdgcn_mfma_f32_16x16x32_bf16(af0, bf, acc[0], 0, 0, 0);
    acc[1] = __builtin_amdgcn_mfma_f32_16x16x32_bf16(af1, bf, acc[1], 0, 0, 0);
  }
}

// Decoder cell leg (C=64): A (16 rows) from swizzled LDS, W from global
// (L2-hot); 4 out-subtiles per wave, one A-read feeds 4 MFMAs.
DI void leg4(f32x4 acc[4], const char* Ab, int l15, int q,
             const u16* __restrict__ W, int wbase) {
  const u16* w0 = W + (size_t)(wbase + l15) * 1024 + q * 8;
  const int sw = (l15 & 7) << 4;
  const char* a0 = Ab + l15 * 2048;
#pragma unroll
  for (int kk = 0; kk < 32; kk++) {
    bf16x8 af = *(const bf16x8*)(a0 + ((q * 16 + kk * 64) ^ sw));
#pragma unroll
    for (int oc = 0; oc < 4; oc++) {
      bf16x8 bf = *(const bf16x8*)(w0 + (size_t)oc * 16384 + kk * 32);
      acc[oc] = __builtin_amdgcn_mfma_f32_16x16x32_bf16(af, bf, acc[oc], 0, 0, 0);
    }
  }
}

// Same, A (16 rows) direct from global (plain cached, e.g. fc3g).
DI void leg4G(f32x4 acc[4], const u16* __restrict__ A, int lda, int rbase,
              const u16* __restrict__ W, int wbase, int l15, int q) {
  const u16* a0 = A + (size_t)(rbase + l15) * lda + q * 8;
  const u16* w0 = W + (size_t)(wbase + l15) * 1024 + q * 8;
#pragma unroll
  for (int kk = 0; kk < 32; kk++) {
    bf16x8 af = *(const bf16x8*)(a0 + kk * 32);
#pragma unroll
    for (int oc = 0; oc < 4; oc++) {
      bf16x8 bf = *(const bf16x8*)(w0 + (size_t)oc * 16384 + kk * 32);
      acc[oc] = __builtin_amdgcn_mfma_f32_16x16x32_bf16(af, bf, acc[oc], 0, 0, 0);
    }
  }
}

// ---------------------------------------------------------------------------
// Conductor: 16 steps x 2 layers. 128 WGs: wm=rows (2x32), wn=h-cols (64x16).
// ---------------------------------------------------------------------------
__global__ __launch_bounds__(256) void conductor_k(
    const float* __restrict__ tt,
    u16* __restrict__ h1b, u16* __restrict__ h2b,
    const u16* __restrict__ Whh0, const u16* __restrict__ Wih1, const u16* __restrict__ Whh1,
    const float* __restrict__ b0v, const float* __restrict__ b1v,
    u16* __restrict__ embs, unsigned* __restrict__ cnt) {
  const int wg = blockIdx.x, wm = wg >> 6, wn = wg & 63;
  const int rbase = wm * 32, cbase = wn * 16;
  __shared__ float gS[32 * 64];
  const int tid = threadIdx.x, lane = tid & 63, wv = tid >> 6;
  const int l15 = lane & 15, q = lane >> 4;
  const int vrow = wv * 1024 + cbase;
  float cc1[2], cc2[2];
  int eb[2], ej[2];
#pragma unroll
  for (int e = 0; e < 2; e++) {
    int idx = tid * 2 + e;
    eb[e] = idx >> 4; ej[e] = idx & 15;
    cc1[e] = tt[(rbase + eb[e]) * 4096 + 2048 + cbase + ej[e]];
    cc2[e] = tt[(rbase + eb[e]) * 4096 + 3072 + cbase + ej[e]];
  }
  unsigned sync_no = 0;
  for (int t = 0; t < 16; t++) {
    const int p = t & 1;
    {  // layer 0 (input is zeros)
      f32x4 acc[2]; acc[0] = (f32x4){0,0,0,0}; acc[1] = (f32x4){0,0,0,0};
      leg1(acc, h1b + (size_t)(p ^ 1) * 65536, 1024, Whh0, rbase, vrow, l15, q);
#pragma unroll
      for (int mi = 0; mi < 2; mi++)
#pragma unroll
        for (int r = 0; r < 4; r++)
          gS[(mi * 16 + q * 4 + r) * 64 + wv * 16 + l15] = acc[mi][r];
      __syncthreads();
#pragma unroll
      for (int e = 0; e < 2; e++) {
        int brr = eb[e], jj = ej[e];
        int b = rbase + brr, col = cbase + jj;
        float gi = gS[brr * 64 + jj]      + b0v[col];
        float gf = gS[brr * 64 + 16 + jj] + b0v[1024 + col];
        float gg = gS[brr * 64 + 32 + jj] + b0v[2048 + col];
        float go = gS[brr * 64 + 48 + jj] + b0v[3072 + col];
        float cn = sigm(gf) * cc1[e] + sigm(gi) * tanh_(gg);
        float hn = sigm(go) * tanh_(cn);
        cc1[e] = cn;
        h1b[(size_t)p * 65536 + b * 1024 + col] = f2b(hn);
      }
    }
    grid_sync(cnt, (++sync_no) * 128u);
    {  // layer 1
      f32x4 acc[2]; acc[0] = (f32x4){0,0,0,0}; acc[1] = (f32x4){0,0,0,0};
      leg1(acc, h1b + (size_t)p * 65536, 1024, Wih1, rbase, vrow, l15, q);
      leg1(acc, h2b + (size_t)(p ^ 1) * 65536, 1024, Whh1, rbase, vrow, l15, q);
#pragma unroll
      for (int mi = 0; mi < 2; mi++)
#pragma unroll
        for (int r = 0; r < 4; r++)
          gS[(mi * 16 + q * 4 + r) * 64 + wv * 16 + l15] = acc[mi][r];
      __syncthreads();
#pragma unroll
      for (int e = 0; e < 2; e++) {
        int brr = eb[e], jj = ej[e];
        int b = rbase + brr, col = cbase + jj;
        float gi = gS[brr * 64 + jj]      + b1v[col];
        float gf = gS[brr * 64 + 16 + jj] + b1v[1024 + col];
        float gg = gS[brr * 64 + 32 + jj] + b1v[2048 + col];
        float go = gS[brr * 64 + 48 + jj] + b1v[3072 + col];
        float cn = sigm(gf) * cc2[e] + sigm(gi) * tanh_(gg);
        float hn = sigm(go) * tanh_(cn);
        cc2[e] = cn;
        u16 hv = f2b(hn);
        h2b[(size_t)p * 65536 + b * 1024 + col] = hv;
        embs[((size_t)t * 64 + b) * 1024 + col] = hv;
      }
    }
    grid_sync(cnt, (++sync_no) * 128u);
  }
}

// ---------------------------------------------------------------------------
// Decoder: 128 WGs x 256 threads. Broadcast barrier; h via sc0sc1+LDS;
// weights L2-resident (per-XCD footprint = 4 MB under wg%8 placement).
//   WGs 0..63  : cell tile 16 rows x 64 cols (wm=wg>>4, wn=wg&15); wave wv
//                owns gate wv (4 out-subtiles). 4x less LLC h-staging.
//   WGs 64..127: fc4 tile 16 rows x 32 out-cols (rb=(wf&3)*16, ostrip=wf>>2),
//                K quartered across waves, LDS reduce. wg 64 = barrier master.
// ---------------------------------------------------------------------------
__global__ __launch_bounds__(256, 2) void decoder_k(
    const u16* __restrict__ fc3g, const u16* __restrict__ base1,
    const float* __restrict__ delta4, const u16* __restrict__ Wfused,
    const u16* __restrict__ Whh1, const u16* __restrict__ Wih2, const u16* __restrict__ Whh2,
    const float* __restrict__ b2v, const u16* __restrict__ f4Wb, const float* __restrict__ f4b,
    u16* __restrict__ dh1b, u16* __restrict__ dh2b, float* __restrict__ outL,
    unsigned* __restrict__ cnt) {
  const int wg = blockIdx.x;
  __shared__ char Lb[65536];
  const int tid = threadIdx.x, lane = tid & 63, wv = tid >> 6;
  const int l15 = lane & 15, q = lane >> 4;
  char* buf0 = Lb;
  char* buf1 = Lb + 32768;
  float* gS = (float*)(Lb + 32768);   // aliases buf1 (dead after legs)
  unsigned gen = 0;
  const int grp = wg & 7;

  if (wg < 64) {
    // ---------------- cell WGs ----------------
    const int wm = wg >> 4, wn = wg & 15;
    const int rbase = wm * 16;
    const int wbase = wv * 1024 + wn * 64;       // W row base (gate wv)
    const int erow = (tid * 4) >> 6, ecol0 = (tid * 4) & 63;
    const int grow = rbase + erow;
    const int colg0 = wn * 64 + ecol0;
    float cc1[4] = {0,0,0,0}, cc2[4] = {0,0,0,0};
    for (int s = 0; s < 256; s++) {
      const int bar = s >> 4, st = s & 15, p = s & 1;
      const u16* g3 = fc3g + (size_t)bar * 262144;
      {  // ---- window A: cell1 ----
        if (st) stage_pair(buf0, dh2b + (size_t)(p ^ 1) * 65536 + rbase * 1024,
                           buf1, dh1b + (size_t)(p ^ 1) * 65536 + rbase * 1024, tid);
        else    stage32(buf0, dh2b + (size_t)(p ^ 1) * 65536 + rbase * 1024, tid);
        __syncthreads();
        f32x4 acc[4];
        acc[0] = (f32x4){0,0,0,0}; acc[1] = (f32x4){0,0,0,0};
        acc[2] = (f32x4){0,0,0,0}; acc[3] = (f32x4){0,0,0,0};
        leg4(acc, buf0, l15, q, Wfused, wbase);
        if (st) leg4(acc, buf1, l15, q, Whh1, wbase);
        else    leg4G(acc, g3, 4096, rbase, Whh1, wbase, l15, q);
        __syncthreads();
#pragma unroll
        for (int oc = 0; oc < 4; oc++)
#pragma unroll
          for (int r = 0; r < 4; r++)
            gS[wv * 1024 + (q * 4 + r) * 64 + oc * 16 + l15] = acc[oc][r];
        __syncthreads();
        size_t bb = ((size_t)bar * 64 + grow) * 4096;
        float bi[4], bfv[4], bg[4], bo[4];
        ld_b4(&base1[bb + colg0], bi);
        ld_b4(&base1[bb + 1024 + colg0], bfv);
        ld_b4(&base1[bb + 2048 + colg0], bg);
        ld_b4(&base1[bb + 3072 + colg0], bo);
        float ci[4] = {0,0,0,0};
        if (st == 0) ld_b4(&g3[(size_t)grow * 4096 + 2048 + colg0], ci);
        float4 di = {0,0,0,0}, df = {0,0,0,0}, dg = {0,0,0,0}, dzo = {0,0,0,0};
        if (s > 0) {
          di  = *(const float4*)&delta4[colg0];
          df  = *(const float4*)&delta4[1024 + colg0];
          dg  = *(const float4*)&delta4[2048 + colg0];
          dzo = *(const float4*)&delta4[3072 + colg0];
        }
        float4 g0 = *(const float4*)&gS[0 * 1024 + erow * 64 + ecol0];
        float4 g1 = *(const float4*)&gS[1 * 1024 + erow * 64 + ecol0];
        float4 g2 = *(const float4*)&gS[2 * 1024 + erow * 64 + ecol0];
        float4 g3v = *(const float4*)&gS[3 * 1024 + erow * 64 + ecol0];
        float hv[4];
#pragma unroll
        for (int e = 0; e < 4; e++) {
          float gi = ((const float*)&g0)[e] + bi[e] + ((const float*)&di)[e];
          float gf = ((const float*)&g1)[e] + bfv[e] + ((const float*)&df)[e];
          float gg = ((const float*)&g2)[e] + bg[e] + ((const float*)&dg)[e];
          float go = ((const float*)&g3v)[e] + bo[e] + ((const float*)&dzo)[e];
          if (st == 0) cc1[e] = ci[e];
          float cn = sigm(gf) * cc1[e] + sigm(gi) * tanh_(gg);
          hv[e] = sigm(go) * tanh_(cn);
          cc1[e] = cn;
        }
        st_h4(dh1b + (size_t)p * 65536 + grow * 1024 + colg0, hv[0], hv[1], hv[2], hv[3]);
      }
      grid_sync_nf(cnt, ++gen, grp, false);
      {  // ---- window B: cell2 ----
        stage32(buf1, dh1b + (size_t)p * 65536 + rbase * 1024, tid);
        __syncthreads();
        f32x4 acc[4];
        acc[0] = (f32x4){0,0,0,0}; acc[1] = (f32x4){0,0,0,0};
        acc[2] = (f32x4){0,0,0,0}; acc[3] = (f32x4){0,0,0,0};
        leg4(acc, buf1, l15, q, Wih2, wbase);
        if (st) leg4(acc, buf0, l15, q, Whh2, wbase);
        else    leg4G(acc, g3 + 1024, 4096, rbase, Whh2, wbase, l15, q);
        __syncthreads();
#pragma unroll
        for (int oc = 0; oc < 4; oc++)
#pragma unroll
          for (int r = 0; r < 4; r++)
            gS[wv * 1024 + (q * 4 + r) * 64 + oc * 16 + l15] = acc[oc][r];
        __syncthreads();
        float ci[4] = {0,0,0,0};
        if (st == 0) ld_b4(&g3[(size_t)grow * 4096 + 3072 + colg0], ci);
        float4 g0 = *(const float4*)&gS[0 * 1024 + erow * 64 + ecol0];
        float4 g1 = *(const float4*)&gS[1 * 1024 + erow * 64 + ecol0];
        float4 g2 = *(const float4*)&gS[2 * 1024 + erow * 64 + ecol0];
        float4 g3v = *(const float4*)&gS[3 * 1024 + erow * 64 + ecol0];
        float hv[4];
#pragma unroll
        for (int e = 0; e < 4; e++) {
          float gi = ((const float*)&g0)[e] + b2v[colg0 + e];
          float gf = ((const float*)&g1)[e] + b2v[1024 + colg0 + e];
          float gg = ((const float*)&g2)[e] + b2v[2048 + colg0 + e];
          float go = ((const float*)&g3v)[e] + b2v[3072 + colg0 + e];
          if (st == 0) cc2[e] = ci[e];
          float cn = sigm(gf) * cc2[e] + sigm(gi) * tanh_(gg);
          hv[e] = sigm(go) * tanh_(cn);
          cc2[e] = cn;
        }
        st_h4(dh2b + (size_t)p * 65536 + grow * 1024 + colg0, hv[0], hv[1], hv[2], hv[3]);
      }
      grid_sync_nf(cnt, ++gen, grp, false);
    }
  } else {
    // ---------------- fc4 WGs ----------------
    const int wf = wg - 64;
    const bool mas = (wf == 0);
    const int rb = (wf & 3) * 16, ostrip = wf >> 2;
    const int kbase = wv * 256;
    const int sw = (l15 & 7) << 4;
    float* gS4 = (float*)Lb;                     // aliases buf0 after legs
    for (int s = 0; s < 256; s++) {
      const int p = s & 1;
      if (s >= 1) {  // window A: logits of step s-1 from dh2b[p^1]
        stage32(buf0, dh2b + (size_t)(p ^ 1) * 65536 + rb * 1024, tid);
        __syncthreads();
        f32x4 a4[2]; a4[0] = (f32x4){0,0,0,0}; a4[1] = (f32x4){0,0,0,0};
        const char* a0 = buf0 + l15 * 2048 + kbase * 2;
        const u16* w0 = f4Wb + (size_t)(ostrip * 32 + l15) * 1024 + kbase + q * 8;
#pragma unroll
        for (int kk = 0; kk < 8; kk++) {
          bf16x8 af = *(const bf16x8*)(a0 + ((q * 16 + kk * 64) ^ sw));
#pragma unroll
          for (int oc = 0; oc < 2; oc++) {
            bf16x8 bf = *(const bf16x8*)(w0 + oc * 16384 + kk * 32);
            a4[oc] = __builtin_amdgcn_mfma_f32_16x16x32_bf16(af, bf, a4[oc], 0, 0, 0);
          }
        }
        __syncthreads();   // buf0 dead -> reuse as partial buffer
#pragma unroll
        for (int oc = 0; oc < 2; oc++)
#pragma unroll
          for (int r = 0; r < 4; r++)
            gS4[wv * 512 + oc * 256 + (q * 4 + r) * 16 + l15] = a4[oc][r];
        __syncthreads();
#pragma unroll
        for (int e = 0; e < 2; e++) {
          int o = tid * 2 + e, row = o >> 5, col = o & 31;
          int oc = col >> 4, c2 = col & 15;
          float v = gS4[oc * 256 + row * 16 + c2] + gS4[512 + oc * 256 + row * 16 + c2]
                  + gS4[1024 + oc * 256 + row * 16 + c2] + gS4[1536 + oc * 256 + row * 16 + c2]
                  + f4b[ostrip * 32 + col];
          outL[((size_t)(rb + row) * 256 + (s - 1)) * 512 + ostrip * 32 + col] = v;
        }
      }
      grid_sync_nf(cnt, ++gen, grp, mas);
      grid_sync_nf(cnt, ++gen, grp, mas);
    }
    {  // tail: logits of step 255 (h2 in dh2b[1])
      stage32(buf0, dh2b + 65536 + rb * 1024, tid);
      __syncthreads();
      f32x4 a4[2]; a4[0] = (f32x4){0,0,0,0}; a4[1] = (f32x4){0,0,0,0};
      const char* a0 = buf0 + l15 * 2048 + kbase * 2;
      const u16* w0 = f4Wb + (size_t)(ostrip * 32 + l15) * 1024 + kbase + q * 8;
#pragma unroll
      for (int kk = 0; kk < 8; kk++) {
        bf16x8 af = *(const bf16x8*)(a0 + ((q * 16 + kk * 64) ^ sw));
#pragma unroll
        for (int oc = 0; oc < 2; oc++) {
          bf16x8 bf = *(const bf16x8*)(w0 + oc * 16384 + kk * 32);
          a4[oc] = __builtin_amdgcn_mfma_f32_16x16x32_bf16(af, bf, a4[oc], 0, 0, 0);
        }
      }
      __syncthreads();
#pragma unroll
      for (int oc = 0; oc < 2; oc++)
#pragma unroll
        for (int r = 0; r < 4; r++)
          gS4[wv * 512 + oc * 256 + (q * 4 + r) * 16 + l15] = a4[oc][r];
      __syncthreads();
#pragma unroll
      for (int e = 0; e < 2; e++) {
        int o = tid * 2 + e, row = o >> 5, col = o & 31;
        int oc = col >> 4, c2 = col & 15;
        float v = gS4[oc * 256 + row * 16 + c2] + gS4[512 + oc * 256 + row * 16 + c2]
                + gS4[1024 + oc * 256 + row * 16 + c2] + gS4[1536 + oc * 256 + row * 16 + c2]
                + f4b[ostrip * 32 + col];
        outL[((size_t)(rb + row) * 256 + 255) * 512 + ostrip * 32 + col] = v;
      }
    }
  }
}

// ---------------------------------------------------------------------------
__global__ __launch_bounds__(256) void latent_k(
    const u16* __restrict__ hT, const float* __restrict__ Wm, const float* __restrict__ bm,
    const float* __restrict__ Ws, const float* __restrict__ bs,
    const float* __restrict__ eps, const float* __restrict__ segemb, const float* __restrict__ Wseg,
    float* __restrict__ dtail, u16* __restrict__ zseg) {
  const int b = blockIdx.x, tid = threadIdx.x;
  __shared__ float ht[128], se[128];
  if (tid < 128) ht[tid] = b2f(hT[b * 128 + tid]);
  else if (tid < 256) se[tid - 128] = segemb[b * 128 + tid - 128];
  __syncthreads();
  for (int n = tid; n < 512; n += 256) {
    float am = 0.f, as = 0.f, ag = 0.f;
    for (int k = 0; k < 128; k++) {
      am += ht[k] * Wm[n * 128 + k];
      as += ht[k] * Ws[n * 128 + k];
      ag += se[k] * Wseg[n * 128 + k];
    }
    am += bm[n]; as += bs[n];
    float sp = fmaxf(as, 0.f) + log1pf(__expf(-fabsf(as)));
    float z = am + eps[b * 512 + n] * sp;
    dtail[b * 512 + n] = am;
    dtail[32768 + b * 512 + n] = sp;
    zseg[b * 1024 + n] = f2b(z);
    zseg[b * 1024 + 512 + n] = f2b(ag);
  }
}

__global__ void split_k(const float* __restrict__ tt, u16* __restrict__ h1b, u16* __restrict__ h2b) {
  int i = blockIdx.x * 256 + threadIdx.x;  // 65536
  int b = i >> 10, j = i & 1023;
  h1b[65536 + i] = f2b(tt[b * 4096 + j]);
  h2b[65536 + i] = f2b(tt[b * 4096 + 1024 + j]);
}

__global__ void f4wt_k(const float* __restrict__ W, u16* __restrict__ Wt) {
  int i = blockIdx.x * 256 + threadIdx.x;  // 1024*512
  int j = i >> 9, k = i & 511;
  Wt[i] = f2b(W[k * 1024 + j]);  // Wt[j][k] = fc4_W[k][j]
}

__global__ void delta4_k(const float* __restrict__ Wih1, const float* __restrict__ b4, float* __restrict__ d4) {
  int n = blockIdx.x * 256 + threadIdx.x;  // 4096
  float a = 0.f;
  for (int j = 0; j < 512; j++) a += Wih1[(size_t)n * 1536 + 1024 + j] * b4[j];
  d4[n] = a;
}

__global__ void init_k(u16* __restrict__ dh2b, unsigned* __restrict__ cnt) {
  int i = blockIdx.x * 256 + threadIdx.x;  // 65536
  dh2b[65536 + i] = 0;
  if (i < 512) cnt[i] = 0;
}

__global__ __launch_bounds__(256) void softmax_k(float* __restrict__ out) {
  __shared__ float red[256];
  float* row = out + (size_t)blockIdx.x * 512;
  const int tid = threadIdx.x;
  float v0 = row[tid], v1 = row[tid + 256];
  red[tid] = fmaxf(v0, v1);
  __syncthreads();
  for (int s = 128; s; s >>= 1) { if (tid < s) red[tid] = fmaxf(red[tid], red[tid + s]); __syncthreads(); }
  float m = red[0];
  __syncthreads();
  float e0 = __expf(v0 - m), e1 = __expf(v1 - m);
  red[tid] = e0 + e1;
  __syncthreads();
  for (int s = 128; s; s >>= 1) { if (tid < s) red[tid] += red[tid + s]; __syncthreads(); }
  float inv = 1.0f / red[0];
  row[tid] = e0 * inv;
  row[tid + 256] = e1 * inv;
}

// ---------------------------------------------------------------------------
// ws layout (77.8 MiB), phase-ordered aliases as round 4.
// ---------------------------------------------------------------------------
extern "C" void kernel_launch(void* const* d_in, const int* in_sizes, int n_in,
                              void* d_out, int out_size, void* d_ws, size_t ws_size,
                              hipStream_t stream) {
  (void)in_sizes; (void)n_in; (void)out_size; (void)ws_size;
  const float* tin    = (const float*)d_in[0];
  const float* segemb = (const float*)d_in[1];
  const float* eps    = (const float*)d_in[2];
  const float* eW0f = (const float*)d_in[3];  const float* eU0f = (const float*)d_in[4];  const float* eb0f = (const float*)d_in[5];
  const float* eW0b = (const float*)d_in[6];  const float* eU0b = (const float*)d_in[7];  const float* eb0b = (const float*)d_in[8];
  const float* eW1f = (const float*)d_in[9];  const float* eU1f = (const float*)d_in[10]; const float* eb1f = (const float*)d_in[11];
  const float* eW1b = (const float*)d_in[12]; const float* eU1b = (const float*)d_in[13]; const float* eb1b = (const float*)d_in[14];
  const float* fmW = (const float*)d_in[15]; const float* fmB = (const float*)d_in[16];
  const float* fsW = (const float*)d_in[17]; const float* fsB = (const float*)d_in[18];
  const float* segW = (const float*)d_in[19];
  const float* fc2W = (const float*)d_in[20]; const float* fc2B = (const float*)d_in[21];
  const float* cU0 = (const float*)d_in[23]; const float* cb0 = (const float*)d_in[24];
  const float* cW1 = (const float*)d_in[25]; const float* cU1 = (const float*)d_in[26]; const float* cb1 = (const float*)d_in[27];
  const float* fc3W = (const float*)d_in[28]; const float* fc3B = (const float*)d_in[29];
  const float* c1W = (const float*)d_in[30]; const float* c1U = (const float*)d_in[31]; const float* c1B = (const float*)d_in[32];
  const float* c2W = (const float*)d_in[33]; const float* c2U = (const float*)d_in[34]; const float* c2B = (const float*)d_in[35];
  const float* f4W = (const float*)d_in[36]; const float* f4B = (const float*)d_in[37];

  char* ws = (char*)d_ws;
  u16* eW0f_b = (u16*)(ws + 0);        u16* eW0b_b = (u16*)(ws + 262144);
  u16* eU0f_b = (u16*)(ws + 524288);   u16* eU0b_b = (u16*)(ws + 557056);
  u16* eW1f_b = (u16*)(ws + 589824);   u16* eW1b_b = (u16*)(ws + 655360);
  u16* eU1f_b = (u16*)(ws + 720896);   u16* eU1b_b = (u16*)(ws + 753664);
  u16* fc2W_b = (u16*)(ws + 786432);
  u16* cU0_b  = (u16*)(ws + 9175040ull);
  u16* cW1_b  = (u16*)(ws + 17563648ull);
  u16* cU1_b  = (u16*)(ws + 25952256ull);
  u16* fc3g   = cU0_b;                 // alias after conductor
  u16* base1  = cW1_b;
  u16* Wfu    = cU1_b;
  char* decb  = ws + 34340864ull;
  u16* c1W_b  = (u16*)(decb + 0);             // 12,582,912 B
  u16* c1U_b  = (u16*)(decb + 12582912ull);   // 8,388,608 B
  u16* c2W_b  = (u16*)(decb + 20971520ull);
  u16* c2U_b  = (u16*)(decb + 29360128ull);
  u16* f4W_b  = (u16*)(decb + 37748736ull);   // 1,048,576 B
  u16* preF   = (u16*)(decb + 0);             // early alias (dead before cvt_late)
  u16* preB   = (u16*)(decb + 8388608ull);
  u16* fc3W_b = (u16*)(decb + 0);             // mid alias (dead before cvt_late)
  u16* f4Wt   = (u16*)(ws + 73138176ull);
  u16* embs   = (u16*)(ws + 74186752ull);
  char* hsr   = ws + 76283904ull;
  u16* hs0    = (u16*)(hsr + 0);              // 4,194,304 B (enc L0 out)
  u16* hT     = (u16*)(hsr + 0);              // late alias
  u16* zseg   = (u16*)(hsr + 16384);
  float* tt   = (float*)(hsr + 147456);
  u16* h1b    = (u16*)(ws + 80478208ull);
  u16* h2b    = (u16*)(ws + 80740352ull);
  u16* dh1b   = (u16*)(ws + 81002496ull);
  u16* dh2b   = (u16*)(ws + 81264640ull);
  float* d4   = (float*)(ws + 81526784ull);
  unsigned* cnt = (unsigned*)(ws + 81543168ull);   // 512 u32: [0] conductor, [128..] decoder
  u16* tin_b  = (u16*)d_out;                  // 16,777,216 B; dead after L0 GEMMs

  // ---- conversion tables ----
  CvtTab te = {};
  {
    const float* s[16] = {tin, eW0f, eW0b, eU0f, eU0b, eW1f, eW1b, eU1f, eU1b,
                          fc2W, cU0, cW1, cU1, fc3W, fc3W, fc3W};
    u16* d[16] = {tin_b, eW0f_b, eW0b_b, eU0f_b, eU0b_b, eW1f_b, eW1b_b, eU1f_b, eU1b_b,
                  fc2W_b, cU0_b, cW1_b, cU1_b, nullptr, nullptr, nullptr};
    unsigned n[16] = {8388608u, 131072u, 131072u, 16384u, 16384u, 32768u, 32768u, 16384u, 16384u,
                      4194304u, 4194304u, 4194304u, 4194304u, 0u, 0u, 0u};
    unsigned c = 0;
    for (int i = 0; i < 16; i++) { te.s[i] = s[i]; te.d[i] = d[i]; te.cum[i] = c; c += n[i] >> 2; }
    te.cum[16] = c;
  }
  CvtTab tm = {};
  {
    unsigned c = 0;
    for (int i = 0; i < 16; i++) { tm.s[i] = fc3W; tm.d[i] = fc3W_b; tm.cum[i] = c; if (i == 0) c += 4194304u >> 2; }
    tm.cum[16] = c;
  }
  CvtTab tl = {};
  {
    const float* s[16] = {c1W, c1U, c2W, c2U, f4W, f4W, f4W, f4W, f4W, f4W, f4W, f4W, f4W, f4W, f4W, f4W};
    u16* d[16] = {c1W_b, c1U_b, c2W_b, c2U_b, f4W_b, nullptr, nullptr, nullptr,
                  nullptr, nullptr, nullptr, nullptr, nullptr, nullptr, nullptr, nullptr};
    unsigned n[16] = {6291456u, 4194304u, 4194304u, 4194304u, 524288u, 0,0,0,0,0,0,0,0,0,0,0};
    unsigned c = 0;
    for (int i = 0; i < 16; i++) { tl.s[i] = s[i]; tl.d[i] = d[i]; tl.cum[i] = c; c += n[i] >> 2; }
    tl.cum[16] = c;
  }

  cvt_k<<<(te.cum[16] + 255) / 256, 256, 0, stream>>>(te);
  init_k<<<256, 256, 0, stream>>>(dh2b, cnt);

  // encoder L0 input projections (rows (b,s) -> permuted to (s,b))
  gemm_bt<<<dim3(4, 256), 256, 0, stream>>>(tin_b, 512, eW0f_b, 512, eb0f, preF, 256, 512, 1 | 4, 64, 256);
  gemm_bt<<<dim3(4, 256), 256, 0, stream>>>(tin_b, 512, eW0b_b, 512, eb0b, preB, 256, 512, 1 | 4, 64, 256);
  enc_rec<<<8, 1024, 0, stream>>>(preF, preB, eU0f_b, eU0b_b, hs0, nullptr);
  gemm_bt<<<dim3(4, 256), 256, 0, stream>>>(hs0, 128, eW1f_b, 128, eb1f, preF, 256, 128, 1, 1, 1);
  gemm_bt<<<dim3(4, 256), 256, 0, stream>>>(hs0, 128, eW1b_b, 128, eb1b, preB, 256, 128, 1, 1, 1);
  enc_rec<<<8, 1024, 0, stream>>>(preF, preB, eU1f_b, eU1b_b, nullptr, hT);
  // latent: z_mean/z_std (f32) to d_out tail; z|seg (bf16) for fc2
  latent_k<<<64, 256, 0, stream>>>(hT, fmW, fmB, fsW, fsB, eps, segemb, segW,
                                   (float*)d_out + 8388608, zseg);
  gemm_bt<<<dim3(64, 1), 256, 0, stream>>>(zseg, 1024, fc2W_b, 1024, fc2B, tt, 4096, 1024, 2, 1, 1);
  split_k<<<256, 256, 0, stream>>>(tt, h1b, h2b);
  conductor_k<<<128, 256, 0, stream>>>(tt, h1b, h2b, cU0_b, cW1_b, cU1_b, cb0, cb1, embs, cnt);
  // decoder precomputes
  cvt_k<<<(tm.cum[16] + 255) / 256, 256, 0, stream>>>(tm);   // fc3W_b into dec region (preF dead)
  gemm_bt<<<dim3(64, 16), 256, 0, stream>>>(embs, 1024, fc3W_b, 1024, fc3B, fc3g, 4096, 1024, 1 | 2, 1, 1);
  cvt_k<<<(tl.cum[16] + 255) / 256, 256, 0, stream>>>(tl);   // dec weights (clobbers fc3W_b alias)
  f4wt_k<<<2048, 256, 0, stream>>>(f4W, f4Wt);
  gemm_bt<<<dim3(16, 64), 256, 0, stream>>>(c1W_b + 1024, 1536, f4Wt, 512, nullptr, Wfu, 1024, 512, 1, 1, 1);
  gemm_bt<<<dim3(64, 16), 256, 0, stream>>>(embs, 1024, c1W_b, 1536, c1B, base1, 4096, 1024, 1, 1, 1);
  delta4_k<<<16, 256, 0, stream>>>(c1W, f4B, d4);
  decoder_k<<<128, 256, 0, stream>>>(fc3g, base1, d4, Wfu, c1U_b, c2W_b, c2U_b, c2B, f4W_b, f4B,
                                     dh1b, dh2b, (float*)d_out, cnt + 128);
  softmax_k<<<16384, 256, 0, stream>>>((float*)d_out);
}

// Round 6
// 7899.471 us; speedup vs baseline: 5.6798x; 5.6798x over previous
//
#include <hip/hip_runtime.h>

typedef unsigned short u16;
typedef __attribute__((ext_vector_type(8))) short bf16x8;
typedef __attribute__((ext_vector_type(4))) float f32x4;

#define DI __device__ __forceinline__

DI float b2f(u16 u) { unsigned v = ((unsigned)u) << 16; float f; __builtin_memcpy(&f, &v, 4); return f; }
DI u16 f2b(float f) { unsigned v; __builtin_memcpy(&v, &f, 4); return (u16)((v + 0x7FFFu + ((v >> 16) & 1u)) >> 16); }
DI float sigm(float x) { return 1.0f / (1.0f + __expf(-x)); }
DI float tanh_(float x) { float e = __expf(-2.0f * fabsf(x)); float t = (1.0f - e) / (1.0f + e); return x < 0.0f ? -t : t; }

// Fenced grid barrier (conductor only; invalidates L2 each use).
DI void grid_sync(unsigned* cnt, unsigned target) {
  __syncthreads();
  if (threadIdx.x == 0) {
    __threadfence();
    __hip_atomic_fetch_add(cnt, 1u, __ATOMIC_RELEASE, __HIP_MEMORY_SCOPE_AGENT);
    while (__hip_atomic_load(cnt, __ATOMIC_ACQUIRE, __HIP_MEMORY_SCOPE_AGENT) < target)
      __builtin_amdgcn_s_sleep(2);
    __threadfence();
  }
  __syncthreads();
}

// Fence-free distributed grid barrier: 8 counters spaced 128 B (one LLC line
// each). Arrival: relaxed add on counter[grp]; detect: lanes 0..7 poll all 8.
// No L2 writeback/invalidate -> weights stay L2-resident. Cross-WG data goes
// sc0/sc1; the leading s_waitcnt vmcnt(0) drains it before arrival.
DI void grid_sync_nf(unsigned* cntb, unsigned gen, int grp) {
  asm volatile("s_waitcnt vmcnt(0)" ::: "memory");
  __syncthreads();
  if (threadIdx.x == 0)
    __hip_atomic_fetch_add(&cntb[grp * 32], 1u, __ATOMIC_RELAXED, __HIP_MEMORY_SCOPE_AGENT);
  if (threadIdx.x < 8) {
    while (__hip_atomic_load(&cntb[threadIdx.x * 32], __ATOMIC_RELAXED, __HIP_MEMORY_SCOPE_AGENT) < gen * 32u)
      __builtin_amdgcn_s_sleep(4);
  }
  __syncthreads();
  __builtin_amdgcn_sched_barrier(0);
}

// LLC-coherent 2-byte store (bypass L1/L2 so remote XCDs see it after vmcnt).
DI void st_h(u16* p, float f) {
  unsigned hv = (unsigned)f2b(f);
  asm volatile("global_store_short %0, %1, off sc0 sc1" :: "v"(p), "v"(hv) : "memory");
}

// Stage 32 KB (16 rows x 2048 B) of h from global (sc0 sc1 = LLC-coherent)
// into LDS with the XOR-16B swizzle (row&7)<<4. 256 threads, 8 chunks each.
DI void stage32(char* lds, const u16* g, int tid) {
  const u16* p = g + tid * 8;
  bf16x8 v0, v1, v2, v3, v4, v5, v6, v7;
  asm volatile("global_load_dwordx4 %0, %1, off sc0 sc1" : "=v"(v0) : "v"(p) : "memory");
  asm volatile("global_load_dwordx4 %0, %1, off sc0 sc1" : "=v"(v1) : "v"(p + 2048) : "memory");
  asm volatile("global_load_dwordx4 %0, %1, off sc0 sc1" : "=v"(v2) : "v"(p + 4096) : "memory");
  asm volatile("global_load_dwordx4 %0, %1, off sc0 sc1" : "=v"(v3) : "v"(p + 6144) : "memory");
  asm volatile("global_load_dwordx4 %0, %1, off sc0 sc1" : "=v"(v4) : "v"(p + 8192) : "memory");
  asm volatile("global_load_dwordx4 %0, %1, off sc0 sc1" : "=v"(v5) : "v"(p + 10240) : "memory");
  asm volatile("global_load_dwordx4 %0, %1, off sc0 sc1" : "=v"(v6) : "v"(p + 12288) : "memory");
  asm volatile("global_load_dwordx4 %0, %1, off sc0 sc1" : "=v"(v7) : "v"(p + 14336) : "memory");
  asm volatile("s_waitcnt vmcnt(0)" ::: "memory");
  __builtin_amdgcn_sched_barrier(0);
  const int b0 = tid * 16;
#pragma unroll
  for (int k = 0; k < 8; k++) {
    int byte = b0 + k * 4096;
    int dst = byte ^ (((byte >> 11) & 7) << 4);
    bf16x8 vv = (k == 0) ? v0 : (k == 1) ? v1 : (k == 2) ? v2 : (k == 3) ? v3
              : (k == 4) ? v4 : (k == 5) ? v5 : (k == 6) ? v6 : v7;
    *(bf16x8*)(lds + dst) = vv;
  }
}

// ---------------------------------------------------------------------------
// Batched f32 -> bf16 conversion (up to 16 tensors per launch; cum in quads).
// ---------------------------------------------------------------------------
struct CvtTab { const float* s[16]; u16* d[16]; unsigned cum[17]; };

__global__ __launch_bounds__(256) void cvt_k(CvtTab t) {
  unsigned g = blockIdx.x * 256 + threadIdx.x;
  if (g >= t.cum[16]) return;
  int j = 0;
#pragma unroll
  for (int k = 1; k < 16; k++) j += (g >= t.cum[k]) ? 1 : 0;
  unsigned e = (g - t.cum[j]) << 2;
  float4 v = *(const float4*)(t.s[j] + e);
  unsigned lo = (unsigned)f2b(v.x) | ((unsigned)f2b(v.y) << 16);
  unsigned hi = (unsigned)f2b(v.z) | ((unsigned)f2b(v.w) << 16);
  uint2 pk; pk.x = lo; pk.y = hi;
  *(uint2*)(t.d[j] + e) = pk;
}

// ---------------------------------------------------------------------------
// Generic C(M,N) = act(A(M,K) @ W(N,K)^T + bias). A,W bf16 row-major, bias f32.
// flags: 1 = bf16 out (else f32), 2 = tanh, 4 = row permute (r=p*permQ+q -> q*permP+p)
// ---------------------------------------------------------------------------
__global__ __launch_bounds__(256) void gemm_bt(
    const u16* __restrict__ A, int lda, const u16* __restrict__ W, int ldw,
    const float* __restrict__ bias, void* __restrict__ Cout,
    int N, int K, int flags, int permP, int permQ) {
  __shared__ u16 As[64 * 72];
  __shared__ u16 Bs[64 * 72];
  const int tid = threadIdx.x, lane = tid & 63, wv = tid >> 6;
  const int wm = wv >> 1, wn = wv & 1;
  const int l15 = lane & 15, q = lane >> 4;
  const int mblk = blockIdx.y * 64, nblk = blockIdx.x * 64;
  f32x4 acc[2][2];
  acc[0][0] = (f32x4){0,0,0,0}; acc[0][1] = (f32x4){0,0,0,0};
  acc[1][0] = (f32x4){0,0,0,0}; acc[1][1] = (f32x4){0,0,0,0};
  for (int kc = 0; kc < K; kc += 64) {
    __syncthreads();
    for (int i = tid; i < 1024; i += 256) {
      int mat = i >> 9, seg = i & 511;
      int row = seg >> 3, k8 = (seg & 7) << 3;
      const u16* src = mat ? W + (size_t)(nblk + row) * ldw + kc + k8
                           : A + (size_t)(mblk + row) * lda + kc + k8;
      u16* dst = (mat ? Bs : As) + row * 72 + k8;
      *(bf16x8*)dst = *(const bf16x8*)src;
    }
    __syncthreads();
#pragma unroll
    for (int ks = 0; ks < 2; ks++) {
      bf16x8 afr[2], bfr[2];
#pragma unroll
      for (int x = 0; x < 2; x++) {
        afr[x] = *(const bf16x8*)&As[(wm * 32 + x * 16 + l15) * 72 + ks * 32 + q * 8];
        bfr[x] = *(const bf16x8*)&Bs[(wn * 32 + x * 16 + l15) * 72 + ks * 32 + q * 8];
      }
#pragma unroll
      for (int mi = 0; mi < 2; mi++)
#pragma unroll
        for (int ni = 0; ni < 2; ni++)
          acc[mi][ni] = __builtin_amdgcn_mfma_f32_16x16x32_bf16(afr[mi], bfr[ni], acc[mi][ni], 0, 0, 0);
    }
  }
#pragma unroll
  for (int mi = 0; mi < 2; mi++)
#pragma unroll
    for (int ni = 0; ni < 2; ni++) {
      int gn = nblk + wn * 32 + ni * 16 + l15;
      float bv = bias ? bias[gn] : 0.0f;
#pragma unroll
      for (int r = 0; r < 4; r++) {
        int gm = mblk + wm * 32 + mi * 16 + q * 4 + r;
        float v = acc[mi][ni][r] + bv;
        if (flags & 2) v = tanh_(v);
        int dr = gm;
        if (flags & 4) { int pp = gm / permQ, qq = gm - pp * permQ; dr = qq * permP + pp; }
        if (flags & 1) ((u16*)Cout)[(size_t)dr * N + gn] = f2b(v);
        else ((float*)Cout)[(size_t)dr * N + gn] = v;
      }
    }
}

// ---------------------------------------------------------------------------
// Encoder LSTM recurrence. grid = 8 blocks: dir = blk&1, batch-group = blk>>1.
// ---------------------------------------------------------------------------
__global__ __launch_bounds__(1024) void enc_rec(
    const u16* __restrict__ pf, const u16* __restrict__ pb,
    const u16* __restrict__ Wf, const u16* __restrict__ Wb,
    u16* __restrict__ hs_out, u16* __restrict__ hT_out) {
  const int dir = blockIdx.x & 1, bg = blockIdx.x >> 1;
  const u16* pre = dir ? pb : pf;
  const u16* Whh = dir ? Wb : Wf;
  const int coff = dir * 64, rbase = bg * 16;
  __shared__ u16 hS[16 * 72];
  __shared__ u16 wS[256 * 72];
  __shared__ float cS[16 * 64];
  __shared__ float gS[16 * 256];
  const int tid = threadIdx.x, lane = tid & 63, wv = tid >> 6;
  const int l15 = lane & 15, q = lane >> 4;
  for (int i = tid; i < 2048; i += 1024) {
    int row = i >> 3, k8 = (i & 7) << 3;
    *(bf16x8*)&wS[row * 72 + k8] = *(const bf16x8*)&Whh[row * 64 + k8];
  }
  for (int i = tid; i < 16 * 72; i += 1024) hS[i] = 0;
  if (tid < 16 * 64) cS[tid] = 0.0f;
  __syncthreads();
  const int br = tid >> 6, j = tid & 63;
  for (int stp = 0; stp < 256; stp++) {
    const int t = dir ? 255 - stp : stp;
    f32x4 acc = (f32x4){0,0,0,0};
#pragma unroll
    for (int ks = 0; ks < 2; ks++) {
      bf16x8 bfr = *(const bf16x8*)&wS[(wv * 16 + l15) * 72 + ks * 32 + q * 8];
      bf16x8 afr = *(const bf16x8*)&hS[l15 * 72 + ks * 32 + q * 8];
      acc = __builtin_amdgcn_mfma_f32_16x16x32_bf16(afr, bfr, acc, 0, 0, 0);
    }
#pragma unroll
    for (int r = 0; r < 4; r++)
      gS[(q * 4 + r) * 256 + wv * 16 + l15] = acc[r];
    __syncthreads();
    const u16* pt = pre + ((size_t)t * 64 + rbase) * 256;
    {
      float gi = gS[br * 256 + j]       + b2f(pt[br * 256 + j]);
      float gf = gS[br * 256 + 64 + j]  + b2f(pt[br * 256 + 64 + j]);
      float gg = gS[br * 256 + 128 + j] + b2f(pt[br * 256 + 128 + j]);
      float go = gS[br * 256 + 192 + j] + b2f(pt[br * 256 + 192 + j]);
      float cn = sigm(gf) * cS[br * 64 + j] + sigm(gi) * tanh_(gg);
      float hn = sigm(go) * tanh_(cn);
      cS[br * 64 + j] = cn;
      u16 hv = f2b(hn);
      hS[br * 72 + j] = hv;
      if (hs_out) hs_out[((size_t)t * 64 + rbase + br) * 128 + coff + j] = hv;
    }
    __syncthreads();
  }
  if (hT_out) hT_out[(rbase + br) * 128 + coff + j] = hS[br * 72 + j];
}

// ---------------------------------------------------------------------------
// Direct-load K=1024 leg (2 M-tiles) — conductor only.
// ---------------------------------------------------------------------------
DI void leg1(f32x4 acc[2], const u16* __restrict__ A, int lda,
             const u16* __restrict__ W, int rbase, int vrow, int l15, int q) {
  const u16* a0 = A + (size_t)(rbase + l15) * lda + q * 8;
  const u16* a1 = A + (size_t)(rbase + 16 + l15) * lda + q * 8;
  const u16* w0 = W + (size_t)(vrow + l15) * 1024 + q * 8;
#pragma unroll
  for (int kk = 0; kk < 32; kk++) {
    bf16x8 af0 = *(const bf16x8*)(a0 + kk * 32);
    bf16x8 af1 = *(const bf16x8*)(a1 + kk * 32);
    bf16x8 bf = *(const bf16x8*)(w0 + kk * 32);
    acc[0] = __builtin_amdgcn_mfma_f32_16x16x32_bf16(af0, bf, acc[0], 0, 0, 0);
    acc[1] = __builtin_amdgcn_mfma_f32_16x16x32_bf16(af1, bf, acc[1], 0, 0, 0);
  }
}

// Decoder cell leg: A (16 rows) from swizzled LDS, W from global (L2-hot).
DI void leg_LG(f32x4* acc, const char* Ab, int l15, int q,
               const u16* __restrict__ W, int vrow) {
  const u16* w0 = W + (size_t)(vrow + l15) * 1024 + q * 8;
  const int sw = (l15 & 7) << 4;
  const char* a0 = Ab + l15 * 2048;
#pragma unroll
  for (int kk = 0; kk < 32; kk++) {
    bf16x8 af = *(const bf16x8*)(a0 + ((q * 16 + kk * 64) ^ sw));
    bf16x8 bf = *(const bf16x8*)(w0 + kk * 32);
    *acc = __builtin_amdgcn_mfma_f32_16x16x32_bf16(af, bf, *acc, 0, 0, 0);
  }
}

// A (16 rows) direct from global (read-only cached, e.g. fc3g).
DI void leg_G(f32x4* acc, const u16* __restrict__ A, int lda,
              const u16* __restrict__ W, int rbase, int vrow, int l15, int q) {
  const u16* a0 = A + (size_t)(rbase + l15) * lda + q * 8;
  const u16* w0 = W + (size_t)(vrow + l15) * 1024 + q * 8;
#pragma unroll
  for (int kk = 0; kk < 32; kk++) {
    bf16x8 af = *(const bf16x8*)(a0 + kk * 32);
    bf16x8 bf = *(const bf16x8*)(w0 + kk * 32);
    *acc = __builtin_amdgcn_mfma_f32_16x16x32_bf16(af, bf, *acc, 0, 0, 0);
  }
}

// ---------------------------------------------------------------------------
// Conductor: 16 steps x 2 layers. 128 WGs: wm=rows (2x32), wn=h-cols (64x16).
// ---------------------------------------------------------------------------
__global__ __launch_bounds__(256) void conductor_k(
    const float* __restrict__ tt,
    u16* __restrict__ h1b, u16* __restrict__ h2b,
    const u16* __restrict__ Whh0, const u16* __restrict__ Wih1, const u16* __restrict__ Whh1,
    const float* __restrict__ b0v, const float* __restrict__ b1v,
    u16* __restrict__ embs, unsigned* __restrict__ cnt) {
  const int wg = blockIdx.x, wm = wg >> 6, wn = wg & 63;
  const int rbase = wm * 32, cbase = wn * 16;
  __shared__ float gS[32 * 64];
  const int tid = threadIdx.x, lane = tid & 63, wv = tid >> 6;
  const int l15 = lane & 15, q = lane >> 4;
  const int vrow = wv * 1024 + cbase;
  float cc1[2], cc2[2];
  int eb[2], ej[2];
#pragma unroll
  for (int e = 0; e < 2; e++) {
    int idx = tid * 2 + e;
    eb[e] = idx >> 4; ej[e] = idx & 15;
    cc1[e] = tt[(rbase + eb[e]) * 4096 + 2048 + cbase + ej[e]];
    cc2[e] = tt[(rbase + eb[e]) * 4096 + 3072 + cbase + ej[e]];
  }
  unsigned sync_no = 0;
  for (int t = 0; t < 16; t++) {
    const int p = t & 1;
    {  // layer 0 (input is zeros)
      f32x4 acc[2]; acc[0] = (f32x4){0,0,0,0}; acc[1] = (f32x4){0,0,0,0};
      leg1(acc, h1b + (size_t)(p ^ 1) * 65536, 1024, Whh0, rbase, vrow, l15, q);
#pragma unroll
      for (int mi = 0; mi < 2; mi++)
#pragma unroll
        for (int r = 0; r < 4; r++)
          gS[(mi * 16 + q * 4 + r) * 64 + wv * 16 + l15] = acc[mi][r];
      __syncthreads();
#pragma unroll
      for (int e = 0; e < 2; e++) {
        int brr = eb[e], jj = ej[e];
        int b = rbase + brr, col = cbase + jj;
        float gi = gS[brr * 64 + jj]      + b0v[col];
        float gf = gS[brr * 64 + 16 + jj] + b0v[1024 + col];
        float gg = gS[brr * 64 + 32 + jj] + b0v[2048 + col];
        float go = gS[brr * 64 + 48 + jj] + b0v[3072 + col];
        float cn = sigm(gf) * cc1[e] + sigm(gi) * tanh_(gg);
        float hn = sigm(go) * tanh_(cn);
        cc1[e] = cn;
        h1b[(size_t)p * 65536 + b * 1024 + col] = f2b(hn);
      }
    }
    grid_sync(cnt, (++sync_no) * 128u);
    {  // layer 1
      f32x4 acc[2]; acc[0] = (f32x4){0,0,0,0}; acc[1] = (f32x4){0,0,0,0};
      leg1(acc, h1b + (size_t)p * 65536, 1024, Wih1, rbase, vrow, l15, q);
      leg1(acc, h2b + (size_t)(p ^ 1) * 65536, 1024, Whh1, rbase, vrow, l15, q);
#pragma unroll
      for (int mi = 0; mi < 2; mi++)
#pragma unroll
        for (int r = 0; r < 4; r++)
          gS[(mi * 16 + q * 4 + r) * 64 + wv * 16 + l15] = acc[mi][r];
      __syncthreads();
#pragma unroll
      for (int e = 0; e < 2; e++) {
        int brr = eb[e], jj = ej[e];
        int b = rbase + brr, col = cbase + jj;
        float gi = gS[brr * 64 + jj]      + b1v[col];
        float gf = gS[brr * 64 + 16 + jj] + b1v[1024 + col];
        float gg = gS[brr * 64 + 32 + jj] + b1v[2048 + col];
        float go = gS[brr * 64 + 48 + jj] + b1v[3072 + col];
        float cn = sigm(gf) * cc2[e] + sigm(gi) * tanh_(gg);
        float hn = sigm(go) * tanh_(cn);
        cc2[e] = cn;
        u16 hv = f2b(hn);
        h2b[(size_t)p * 65536 + b * 1024 + col] = hv;
        embs[((size_t)t * 64 + b) * 1024 + col] = hv;
      }
    }
    grid_sync(cnt, (++sync_no) * 128u);
  }
}

// ---------------------------------------------------------------------------
// Decoder: 256 WGs x 256 threads (1 WG/CU). Round-4 structure + dedicated gS
// (no buf1 alias) so buf1 retains dh1b[p^1] from window B(s-1): window A
// stages ONLY dh2b (one 32 KB stage, one LLC round trip instead of two).
//   All WGs: cell1+cell2 tile (wm*16 rows, wn*16 cols); 4 waves = 4 gates.
//   Even-wn WGs also compute one 16x16 fc4 out-tile from staged buf0.
// ---------------------------------------------------------------------------
__global__ __launch_bounds__(256, 2) void decoder_k(
    const u16* __restrict__ fc3g, const u16* __restrict__ base1,
    const float* __restrict__ delta4, const u16* __restrict__ Wfused,
    const u16* __restrict__ Whh1, const u16* __restrict__ Wih2, const u16* __restrict__ Whh2,
    const float* __restrict__ b2v, const u16* __restrict__ f4Wb, const float* __restrict__ f4b,
    u16* __restrict__ dh1b, u16* __restrict__ dh2b, float* __restrict__ outL,
    unsigned* __restrict__ cnt) {
  const int wg = blockIdx.x;
  __shared__ char Lb[81920];          // buf0 32K | buf1 32K | gS 16K (no alias)
  const int tid = threadIdx.x, lane = tid & 63, wv = tid >> 6;
  const int l15 = lane & 15, q = lane >> 4;
  char* buf0 = Lb;
  char* buf1 = Lb + 32768;
  float* gS = (float*)(Lb + 65536);
  unsigned gen = 0;
  const int grp = wg & 7;
  const int wm = wg >> 6, wn = wg & 63;
  const int rbase = wm * 16, cbase = wn * 16;
  const int vrow = wv * 1024 + cbase;
  const int erow = tid >> 4, ecol = tid & 15;
  const int grow = rbase + erow, colg = cbase + ecol;
  const bool doF4 = (wn & 1) == 0;
  const int orow = (wn >> 1) * 16;    // fc4 out-col tile
  float cc1 = 0.f, cc2 = 0.f;
  for (int s = 0; s < 256; s++) {
    const int bar = s >> 4, st = s & 15, p = s & 1;
    const u16* g3 = fc3g + (size_t)bar * 262144;
    {  // ---- window A: cell1 (+ fc4 of step s-1 on even-wn WGs) ----
      // buf1 still holds dh1b[p^1], staged in window B(s-1); only dh2b needed.
      stage32(buf0, dh2b + (size_t)(p ^ 1) * 65536 + rbase * 1024, tid);
      __syncthreads();
      f32x4 acc = (f32x4){0,0,0,0};
      leg_LG(&acc, buf0, l15, q, Wfused, vrow);
      if (st) leg_LG(&acc, buf1, l15, q, Whh1, vrow);
      else    leg_G(&acc, g3, 4096, Whh1, rbase, vrow, l15, q);
#pragma unroll
      for (int r = 0; r < 4; r++)
        gS[wv * 256 + (q * 4 + r) * 16 + l15] = acc[r];
      __syncthreads();
      size_t bb = ((size_t)bar * 64 + grow) * 4096;
      float gi = gS[0 * 256 + erow * 16 + ecol] + b2f(base1[bb + colg]);
      float gf = gS[1 * 256 + erow * 16 + ecol] + b2f(base1[bb + 1024 + colg]);
      float gg = gS[2 * 256 + erow * 16 + ecol] + b2f(base1[bb + 2048 + colg]);
      float go = gS[3 * 256 + erow * 16 + ecol] + b2f(base1[bb + 3072 + colg]);
      if (s > 0) {
        gi += delta4[colg]; gf += delta4[1024 + colg];
        gg += delta4[2048 + colg]; go += delta4[3072 + colg];
      }
      if (st == 0) cc1 = b2f(g3[(size_t)grow * 4096 + 2048 + colg]);
      float cn = sigm(gf) * cc1 + sigm(gi) * tanh_(gg);
      float hn = sigm(go) * tanh_(cn);
      cc1 = cn;
      st_h(dh1b + (size_t)p * 65536 + grow * 1024 + colg, hn);
      if (doF4 && s >= 1) {  // fc4 logits of step s-1 from buf0 (= h2[s-1])
        __syncthreads();     // gS gate reads done; reuse gS for fc4 partials
        f32x4 a4 = (f32x4){0,0,0,0};
        {
          const int kbase = wv * 256;
          const u16* w0 = f4Wb + (size_t)(orow + l15) * 1024 + kbase + q * 8;
          const int sw = (l15 & 7) << 4;
          const char* a0 = buf0 + l15 * 2048 + kbase * 2;
#pragma unroll
          for (int kk = 0; kk < 8; kk++) {
            bf16x8 af = *(const bf16x8*)(a0 + ((q * 16 + kk * 64) ^ sw));
            bf16x8 bf = *(const bf16x8*)(w0 + kk * 32);
            a4 = __builtin_amdgcn_mfma_f32_16x16x32_bf16(af, bf, a4, 0, 0, 0);
          }
        }
#pragma unroll
        for (int r = 0; r < 4; r++)
          gS[wv * 256 + (q * 4 + r) * 16 + l15] = a4[r];
        __syncthreads();
        float v = gS[tid] + gS[256 + tid] + gS[512 + tid] + gS[768 + tid]
                + f4b[orow + ecol];
        outL[((size_t)(rbase + erow) * 256 + (s - 1)) * 512 + orow + ecol] = v;
      }
    }
    grid_sync_nf(cnt, ++gen, grp);
    {  // ---- window B: cell2 ----
      stage32(buf1, dh1b + (size_t)p * 65536 + rbase * 1024, tid);
      __syncthreads();
      f32x4 acc = (f32x4){0,0,0,0};
      leg_LG(&acc, buf1, l15, q, Wih2, vrow);
      if (st) leg_LG(&acc, buf0, l15, q, Whh2, vrow);
      else    leg_G(&acc, g3 + 1024, 4096, Whh2, rbase, vrow, l15, q);
#pragma unroll
      for (int r = 0; r < 4; r++)
        gS[wv * 256 + (q * 4 + r) * 16 + l15] = acc[r];
      __syncthreads();
      float gi = gS[0 * 256 + erow * 16 + ecol] + b2v[colg];
      float gf = gS[1 * 256 + erow * 16 + ecol] + b2v[1024 + colg];
      float gg = gS[2 * 256 + erow * 16 + ecol] + b2v[2048 + colg];
      float go = gS[3 * 256 + erow * 16 + ecol] + b2v[3072 + colg];
      if (st == 0) cc2 = b2f(g3[(size_t)grow * 4096 + 3072 + colg]);
      float cn = sigm(gf) * cc2 + sigm(gi) * tanh_(gg);
      float hn = sigm(go) * tanh_(cn);
      cc2 = cn;
      st_h(dh2b + (size_t)p * 65536 + grow * 1024 + colg, hn);
    }
    grid_sync_nf(cnt, ++gen, grp);
  }
  if (doF4) {  // tail: fc4 logits of step 255 (h2 in dh2b[1])
    stage32(buf0, dh2b + 65536 + rbase * 1024, tid);
    __syncthreads();
    f32x4 a4 = (f32x4){0,0,0,0};
    {
      const int kbase = wv * 256;
      const u16* w0 = f4Wb + (size_t)(orow + l15) * 1024 + kbase + q * 8;
      const int sw = (l15 & 7) << 4;
      const char* a0 = buf0 + l15 * 2048 + kbase * 2;
#pragma unroll
      for (int kk = 0; kk < 8; kk++) {
        bf16x8 af = *(const bf16x8*)(a0 + ((q * 16 + kk * 64) ^ sw));
        bf16x8 bf = *(const bf16x8*)(w0 + kk * 32);
        a4 = __builtin_amdgcn_mfma_f32_16x16x32_bf16(af, bf, a4, 0, 0, 0);
      }
    }
#pragma unroll
    for (int r = 0; r < 4; r++)
      gS[wv * 256 + (q * 4 + r) * 16 + l15] = a4[r];
    __syncthreads();
    float v = gS[tid] + gS[256 + tid] + gS[512 + tid] + gS[768 + tid]
            + f4b[orow + ecol];
    outL[((size_t)(rbase + erow) * 256 + 255) * 512 + orow + ecol] = v;
  }
}

// ---------------------------------------------------------------------------
__global__ __launch_bounds__(256) void latent_k(
    const u16* __restrict__ hT, const float* __restrict__ Wm, const float* __restrict__ bm,
    const float* __restrict__ Ws, const float* __restrict__ bs,
    const float* __restrict__ eps, const float* __restrict__ segemb, const float* __restrict__ Wseg,
    float* __restrict__ dtail, u16* __restrict__ zseg) {
  const int b = blockIdx.x, tid = threadIdx.x;
  __shared__ float ht[128], se[128];
  if (tid < 128) ht[tid] = b2f(hT[b * 128 + tid]);
  else if (tid < 256) se[tid - 128] = segemb[b * 128 + tid - 128];
  __syncthreads();
  for (int n = tid; n < 512; n += 256) {
    float am = 0.f, as = 0.f, ag = 0.f;
    for (int k = 0; k < 128; k++) {
      am += ht[k] * Wm[n * 128 + k];
      as += ht[k] * Ws[n * 128 + k];
      ag += se[k] * Wseg[n * 128 + k];
    }
    am += bm[n]; as += bs[n];
    float sp = fmaxf(as, 0.f) + log1pf(__expf(-fabsf(as)));
    float z = am + eps[b * 512 + n] * sp;
    dtail[b * 512 + n] = am;
    dtail[32768 + b * 512 + n] = sp;
    zseg[b * 1024 + n] = f2b(z);
    zseg[b * 1024 + 512 + n] = f2b(ag);
  }
}

__global__ void split_k(const float* __restrict__ tt, u16* __restrict__ h1b, u16* __restrict__ h2b) {
  int i = blockIdx.x * 256 + threadIdx.x;  // 65536
  int b = i >> 10, j = i & 1023;
  h1b[65536 + i] = f2b(tt[b * 4096 + j]);
  h2b[65536 + i] = f2b(tt[b * 4096 + 1024 + j]);
}

__global__ void f4wt_k(const float* __restrict__ W, u16* __restrict__ Wt) {
  int i = blockIdx.x * 256 + threadIdx.x;  // 1024*512
  int j = i >> 9, k = i & 511;
  Wt[i] = f2b(W[k * 1024 + j]);  // Wt[j][k] = fc4_W[k][j]
}

__global__ void delta4_k(const float* __restrict__ Wih1, const float* __restrict__ b4, float* __restrict__ d4) {
  int n = blockIdx.x * 256 + threadIdx.x;  // 4096
  float a = 0.f;
  for (int j = 0; j < 512; j++) a += Wih1[(size_t)n * 1536 + 1024 + j] * b4[j];
  d4[n] = a;
}

__global__ void init_k(u16* __restrict__ dh2b, unsigned* __restrict__ cnt) {
  int i = blockIdx.x * 256 + threadIdx.x;  // 65536
  dh2b[65536 + i] = 0;
  if (i < 512) cnt[i] = 0;
}

__global__ __launch_bounds__(256) void softmax_k(float* __restrict__ out) {
  __shared__ float red[256];
  float* row = out + (size_t)blockIdx.x * 512;
  const int tid = threadIdx.x;
  float v0 = row[tid], v1 = row[tid + 256];
  red[tid] = fmaxf(v0, v1);
  __syncthreads();
  for (int s = 128; s; s >>= 1) { if (tid < s) red[tid] = fmaxf(red[tid], red[tid + s]); __syncthreads(); }
  float m = red[0];
  __syncthreads();
  float e0 = __expf(v0 - m), e1 = __expf(v1 - m);
  red[tid] = e0 + e1;
  __syncthreads();
  for (int s = 128; s; s >>= 1) { if (tid < s) red[tid] += red[tid + s]; __syncthreads(); }
  float inv = 1.0f / red[0];
  row[tid] = e0 * inv;
  row[tid + 256] = e1 * inv;
}

// ---------------------------------------------------------------------------
// ws layout (77.8 MiB), phase-ordered aliases as round 4.
// ---------------------------------------------------------------------------
extern "C" void kernel_launch(void* const* d_in, const int* in_sizes, int n_in,
                              void* d_out, int out_size, void* d_ws, size_t ws_size,
                              hipStream_t stream) {
  (void)in_sizes; (void)n_in; (void)out_size; (void)ws_size;
  const float* tin    = (const float*)d_in[0];
  const float* segemb = (const float*)d_in[1];
  const float* eps    = (const float*)d_in[2];
  const float* eW0f = (const float*)d_in[3];  const float* eU0f = (const float*)d_in[4];  const float* eb0f = (const float*)d_in[5];
  const float* eW0b = (const float*)d_in[6];  const float* eU0b = (const float*)d_in[7];  const float* eb0b = (const float*)d_in[8];
  const float* eW1f = (const float*)d_in[9];  const float* eU1f = (const float*)d_in[10]; const float* eb1f = (const float*)d_in[11];
  const float* eW1b = (const float*)d_in[12]; const float* eU1b = (const float*)d_in[13]; const float* eb1b = (const float*)d_in[14];
  const float* fmW = (const float*)d_in[15]; const float* fmB = (const float*)d_in[16];
  const float* fsW = (const float*)d_in[17]; const float* fsB = (const float*)d_in[18];
  const float* segW = (const float*)d_in[19];
  const float* fc2W = (const float*)d_in[20]; const float* fc2B = (const float*)d_in[21];
  const float* cU0 = (const float*)d_in[23]; const float* cb0 = (const float*)d_in[24];
  const float* cW1 = (const float*)d_in[25]; const float* cU1 = (const float*)d_in[26]; const float* cb1 = (const float*)d_in[27];
  const float* fc3W = (const float*)d_in[28]; const float* fc3B = (const float*)d_in[29];
  const float* c1W = (const float*)d_in[30]; const float* c1U = (const float*)d_in[31]; const float* c1B = (const float*)d_in[32];
  const float* c2W = (const float*)d_in[33]; const float* c2U = (const float*)d_in[34]; const float* c2B = (const float*)d_in[35];
  const float* f4W = (const float*)d_in[36]; const float* f4B = (const float*)d_in[37];

  char* ws = (char*)d_ws;
  u16* eW0f_b = (u16*)(ws + 0);        u16* eW0b_b = (u16*)(ws + 262144);
  u16* eU0f_b = (u16*)(ws + 524288);   u16* eU0b_b = (u16*)(ws + 557056);
  u16* eW1f_b = (u16*)(ws + 589824);   u16* eW1b_b = (u16*)(ws + 655360);
  u16* eU1f_b = (u16*)(ws + 720896);   u16* eU1b_b = (u16*)(ws + 753664);
  u16* fc2W_b = (u16*)(ws + 786432);
  u16* cU0_b  = (u16*)(ws + 9175040ull);
  u16* cW1_b  = (u16*)(ws + 17563648ull);
  u16* cU1_b  = (u16*)(ws + 25952256ull);
  u16* fc3g   = cU0_b;                 // alias after conductor
  u16* base1  = cW1_b;
  u16* Wfu    = cU1_b;
  char* decb  = ws + 34340864ull;
  u16* c1W_b  = (u16*)(decb + 0);             // 12,582,912 B
  u16* c1U_b  = (u16*)(decb + 12582912ull);   // 8,388,608 B
  u16* c2W_b  = (u16*)(decb + 20971520ull);
  u16* c2U_b  = (u16*)(decb + 29360128ull);
  u16* f4W_b  = (u16*)(decb + 37748736ull);   // 1,048,576 B
  u16* preF   = (u16*)(decb + 0);             // early alias (dead before cvt_late)
  u16* preB   = (u16*)(decb + 8388608ull);
  u16* fc3W_b = (u16*)(decb + 0);             // mid alias (dead before cvt_late)
  u16* f4Wt   = (u16*)(ws + 73138176ull);
  u16* embs   = (u16*)(ws + 74186752ull);
  char* hsr   = ws + 76283904ull;
  u16* hs0    = (u16*)(hsr + 0);              // 4,194,304 B (enc L0 out)
  u16* hT     = (u16*)(hsr + 0);              // late alias
  u16* zseg   = (u16*)(hsr + 16384);
  float* tt   = (float*)(hsr + 147456);
  u16* h1b    = (u16*)(ws + 80478208ull);
  u16* h2b    = (u16*)(ws + 80740352ull);
  u16* dh1b   = (u16*)(ws + 81002496ull);
  u16* dh2b   = (u16*)(ws + 81264640ull);
  float* d4   = (float*)(ws + 81526784ull);
  unsigned* cnt = (unsigned*)(ws + 81543168ull);   // 512 u32: [0] conductor, [128..] decoder
  u16* tin_b  = (u16*)d_out;                  // 16,777,216 B; dead after L0 GEMMs

  // ---- conversion tables ----
  CvtTab te = {};
  {
    const float* s[16] = {tin, eW0f, eW0b, eU0f, eU0b, eW1f, eW1b, eU1f, eU1b,
                          fc2W, cU0, cW1, cU1, fc3W, fc3W, fc3W};
    u16* d[16] = {tin_b, eW0f_b, eW0b_b, eU0f_b, eU0b_b, eW1f_b, eW1b_b, eU1f_b, eU1b_b,
                  fc2W_b, cU0_b, cW1_b, cU1_b, nullptr, nullptr, nullptr};
    unsigned n[16] = {8388608u, 131072u, 131072u, 16384u, 16384u, 32768u, 32768u, 16384u, 16384u,
                      4194304u, 4194304u, 4194304u, 4194304u, 0u, 0u, 0u};
    unsigned c = 0;
    for (int i = 0; i < 16; i++) { te.s[i] = s[i]; te.d[i] = d[i]; te.cum[i] = c; c += n[i] >> 2; }
    te.cum[16] = c;
  }
  CvtTab tm = {};
  {
    unsigned c = 0;
    for (int i = 0; i < 16; i++) { tm.s[i] = fc3W; tm.d[i] = fc3W_b; tm.cum[i] = c; if (i == 0) c += 4194304u >> 2; }
    tm.cum[16] = c;
  }
  CvtTab tl = {};
  {
    const float* s[16] = {c1W, c1U, c2W, c2U, f4W, f4W, f4W, f4W, f4W, f4W, f4W, f4W, f4W, f4W, f4W, f4W};
    u16* d[16] = {c1W_b, c1U_b, c2W_b, c2U_b, f4W_b, nullptr, nullptr, nullptr,
                  nullptr, nullptr, nullptr, nullptr, nullptr, nullptr, nullptr, nullptr};
    unsigned n[16] = {6291456u, 4194304u, 4194304u, 4194304u, 524288u, 0,0,0,0,0,0,0,0,0,0,0};
    unsigned c = 0;
    for (int i = 0; i < 16; i++) { tl.s[i] = s[i]; tl.d[i] = d[i]; tl.cum[i] = c; c += n[i] >> 2; }
    tl.cum[16] = c;
  }

  cvt_k<<<(te.cum[16] + 255) / 256, 256, 0, stream>>>(te);
  init_k<<<256, 256, 0, stream>>>(dh2b, cnt);

  // encoder L0 input projections (rows (b,s) -> permuted to (s,b))
  gemm_bt<<<dim3(4, 256), 256, 0, stream>>>(tin_b, 512, eW0f_b, 512, eb0f, preF, 256, 512, 1 | 4, 64, 256);
  gemm_bt<<<dim3(4, 256), 256, 0, stream>>>(tin_b, 512, eW0b_b, 512, eb0b, preB, 256, 512, 1 | 4, 64, 256);
  enc_rec<<<8, 1024, 0, stream>>>(preF, preB, eU0f_b, eU0b_b, hs0, nullptr);
  gemm_bt<<<dim3(4, 256), 256, 0, stream>>>(hs0, 128, eW1f_b, 128, eb1f, preF, 256, 128, 1, 1, 1);
  gemm_bt<<<dim3(4, 256), 256, 0, stream>>>(hs0, 128, eW1b_b, 128, eb1b, preB, 256, 128, 1, 1, 1);
  enc_rec<<<8, 1024, 0, stream>>>(preF, preB, eU1f_b, eU1b_b, nullptr, hT);
  // latent: z_mean/z_std (f32) to d_out tail; z|seg (bf16) for fc2
  latent_k<<<64, 256, 0, stream>>>(hT, fmW, fmB, fsW, fsB, eps, segemb, segW,
                                   (float*)d_out + 8388608, zseg);
  gemm_bt<<<dim3(64, 1), 256, 0, stream>>>(zseg, 1024, fc2W_b, 1024, fc2B, tt, 4096, 1024, 2, 1, 1);
  split_k<<<256, 256, 0, stream>>>(tt, h1b, h2b);
  conductor_k<<<128, 256, 0, stream>>>(tt, h1b, h2b, cU0_b, cW1_b, cU1_b, cb0, cb1, embs, cnt);
  // decoder precomputes
  cvt_k<<<(tm.cum[16] + 255) / 256, 256, 0, stream>>>(tm);   // fc3W_b into dec region (preF dead)
  gemm_bt<<<dim3(64, 16), 256, 0, stream>>>(embs, 1024, fc3W_b, 1024, fc3B, fc3g, 4096, 1024, 1 | 2, 1, 1);
  cvt_k<<<(tl.cum[16] + 255) / 256, 256, 0, stream>>>(tl);   // dec weights (clobbers fc3W_b alias)
  f4wt_k<<<2048, 256, 0, stream>>>(f4W, f4Wt);
  gemm_bt<<<dim3(16, 64), 256, 0, stream>>>(c1W_b + 1024, 1536, f4Wt, 512, nullptr, Wfu, 1024, 512, 1, 1, 1);
  gemm_bt<<<dim3(64, 16), 256, 0, stream>>>(embs, 1024, c1W_b, 1536, c1B, base1, 4096, 1024, 1, 1, 1);
  delta4_k<<<16, 256, 0, stream>>>(c1W, f4B, d4);
  decoder_k<<<256, 256, 0, stream>>>(fc3g, base1, d4, Wfu, c1U_b, c2W_b, c2U_b, c2B, f4W_b, f4B,
                                     dh1b, dh2b, (float*)d_out, cnt + 128);
  softmax_k<<<16384, 256, 0, stream>>>((float*)d_out);
}